// Round 19
// baseline (393.189 us; speedup 1.0000x reference)
//
#include <hip/hip_runtime.h>

// Swin window attention, fused register-resident MFMA pipeline. 1 block
// (6 waves) per window; wave w owns head w. B=4096, N=64, C=180, H=6, D=30.
//
// Round-19 = round-18 (282.3 us champion) + qkv GEMM fully merged:
//   - v-pass folded into the qk-pass: per ks, 24 MFMAs (4 qk-swapped +
//     2 v-normal) share ONE xf load set. Deletes 24 ds_read_b128/wave,
//     one fence, and one full dependent chain from the window critical path.
//   - pack order: vf FIRST (av dies early), then qf/kf -- keeps the pack
//     transient at ~112-120 regs (acc 96 + xf 16 peak in the GEMM loop).
//   - fused softmax+PV per it (r18), no-max softmax (r12), bias as VALU add
//     with loads issued under the QKT MFMAs (r18).
//   Tripwire: FETCH/WRITE balloon = spill -> revert to r18, declare plateau.
//
// d_ws (prep_w fills every launch):
//   [0)       wqkvT  bf16 [576][192]  oc = h*96 + sec*32 + d  (0=q,1=k,2=v)
//   [221184)  wprojT bf16 [192][192]  n-major
//   [294912)  relb   f32  [6][64][64] pre-gathered rel-pos bias
//
// LDS: one [64][200] short buffer (x bf16, later z bf16). 25.6 KB.
//
// Fragment-permutation trick (verified r2-r18): MFMA contracts A-slot(g,s)
// with B-slot(g,s); q/k fragments carry d(g,s)=16*(s>=4)+4g+(s&3) and P/V
// fragments carry j(g,s,k2)=32k2+16*(s>=4)+4g+(s&3) -- identical bijections
// on both operands, so no cross-lane traffic anywhere.

typedef __bf16 bf16;
typedef bf16 bf16x8 __attribute__((ext_vector_type(8)));
typedef float f32x4 __attribute__((ext_vector_type(4)));

#define MFMA(a, b, c) __builtin_amdgcn_mfma_f32_16x16x32_bf16(a, b, c, 0, 0, 0)

__global__ void prep_w(const float* __restrict__ wqkv,
                       const float* __restrict__ wproj,
                       const float* __restrict__ btab,
                       bf16* __restrict__ wqkvT,
                       bf16* __restrict__ wprojT,
                       float* __restrict__ relb)
{
    const int idx = blockIdx.x * 256 + threadIdx.x;
    if (idx < 110592) {                          // wqkvT [576][192]
        const int oc = idx / 192, kk = idx - oc * 192;
        const int h = oc / 96, r = oc - h * 96;
        const int sec = r >> 5, d = r & 31;
        wqkvT[idx] = (bf16)((kk < 180 && d < 30) ? wqkv[kk * 540 + sec * 180 + h * 30 + d] : 0.f);
    } else if (idx < 147456) {                   // wprojT [192][192]
        const int r = idx - 110592;
        const int n = r / 192, k = r - n * 192;
        wprojT[r] = (bf16)((n < 180 && k < 180) ? wproj[k * 180 + n] : 0.f);
    } else if (idx < 172032) {                   // relb [6][64][64]
        const int r = idx - 147456;
        const int h = r >> 12;
        const int ij = r & 4095;
        const int i = ij >> 6, j = ij & 63;
        const int rel = ((i >> 3) - (j >> 3) + 7) * 15 + ((i & 7) - (j & 7) + 7);
        relb[r] = btab[rel * 6 + h];
    }
}

__device__ __forceinline__ unsigned pack2(float a, float b) {
    return (unsigned)__builtin_bit_cast(unsigned short, (bf16)a)
         | ((unsigned)__builtin_bit_cast(unsigned short, (bf16)b) << 16);
}

__global__ __launch_bounds__(384, 4)
void swin_mfma(const float* __restrict__ xg_all,
               const float* __restrict__ mask_all,
               const float* __restrict__ bproj,
               const bf16* __restrict__ wqkvT,
               const bf16* __restrict__ wprojT,
               const float* __restrict__ relb,
               float* __restrict__ outg)
{
    __shared__ __align__(16) short xb[64 * 200];   // x bf16, later z bf16

    const int b    = blockIdx.x;
    const int tid  = threadIdx.x;
    const int w    = tid >> 6;                     // wave = head, 0..5
    const int lane = tid & 63;
    const int l15  = lane & 15;
    const int g    = lane >> 4;                    // 0..3

    const float* xg    = xg_all + (size_t)b * 11520;
    const float* maskw = mask_all + (size_t)(b & 1023) * 4096;

    // ---- phase 1: x -> bf16 xb. Batch loads (7-8 float4/thread), then cvt.
    {
        float4 xv[7];
        #pragma unroll
        for (int u = 0; u < 7; u++)
            xv[u] = *reinterpret_cast<const float4*>(xg + 4 * (tid + 384 * u));
        float4 xt;
        if (tid < 192) xt = *reinterpret_cast<const float4*>(xg + 4 * (2688 + tid));
        for (int e = tid; e < 640; e += 384) {     // zero pad cols [180..200)
            const int i = e / 10;
            ((unsigned*)(xb + i * 200 + 180))[e - i * 10] = 0u;
        }
        #pragma unroll
        for (int u = 0; u < 7; u++) {
            const int e = tid + 384 * u;           // float4 index
            const int i = e / 45;
            const int c = 4 * e - i * 180;
            *reinterpret_cast<unsigned*>(xb + i * 200 + c)     = pack2(xv[u].x, xv[u].y);
            *reinterpret_cast<unsigned*>(xb + i * 200 + c + 2) = pack2(xv[u].z, xv[u].w);
        }
        if (tid < 192) {
            const int e = 2688 + tid;
            const int i = e / 45;
            const int c = 4 * e - i * 180;
            *reinterpret_cast<unsigned*>(xb + i * 200 + c)     = pack2(xt.x, xt.y);
            *reinterpret_cast<unsigned*>(xb + i * 200 + c + 2) = pack2(xt.z, xt.w);
        }
    }
    __syncthreads();

    const bf16* wqh = wqkvT + (size_t)(w * 96) * 192;
    const int rowoff = l15 * 192 + 8 * g;

    // ---- phase 2qkv (MERGED): q,k (swapped mfma) AND v (normal mfma) in one
    // pass over ks -- one xf load set feeds 24 MFMAs. acc 96 + xf 16 regs.
    bf16x8 qf[4], kf[4];                           // slot s <-> d = 16*(s>=4)+4g+(s&3)
    bf16x8 vf[2][2];                               // [cv][k2], token-permuted
    {
        f32x4 aqk[4][4];                           // [ct][tt] ct: q0,q1,k0,k1
        f32x4 av[4][2];                            // [tt][cv]
        #pragma unroll
        for (int ct = 0; ct < 4; ct++)
            #pragma unroll
            for (int tt = 0; tt < 4; tt++) aqk[ct][tt] = (f32x4)0.f;
        #pragma unroll
        for (int tt = 0; tt < 4; tt++) { av[tt][0] = (f32x4)0.f; av[tt][1] = (f32x4)0.f; }

        #pragma unroll
        for (int ks = 0; ks < 6; ks++) {
            bf16x8 xf[4];
            #pragma unroll
            for (int tt = 0; tt < 4; tt++)
                xf[tt] = *reinterpret_cast<const bf16x8*>(xb + (16 * tt + l15) * 200 + 32 * ks + 8 * g);
            __builtin_amdgcn_s_setprio(1);
            #pragma unroll
            for (int ct = 0; ct < 4; ct++) {
                const bf16x8 wf = *reinterpret_cast<const bf16x8*>(wqh + ct * 3072 + rowoff + 32 * ks);
                #pragma unroll
                for (int tt = 0; tt < 4; tt++)
                    aqk[ct][tt] = MFMA(wf, xf[tt], aqk[ct][tt]);
            }
            #pragma unroll
            for (int cv = 0; cv < 2; cv++) {
                const bf16x8 wf = *reinterpret_cast<const bf16x8*>(wqh + (4 + cv) * 3072 + rowoff + 32 * ks);
                #pragma unroll
                for (int tt = 0; tt < 4; tt++)
                    av[tt][cv] = MFMA(xf[tt], wf, av[tt][cv]);
            }
            __builtin_amdgcn_s_setprio(0);
        }

        // pack vf FIRST (av dies early), then qf/kf (aqk dies as packed)
        #pragma unroll
        for (int cv = 0; cv < 2; cv++)
            #pragma unroll
            for (int k2 = 0; k2 < 2; k2++)
                #pragma unroll
                for (int s = 0; s < 8; s++)
                    vf[cv][k2][s] = (bf16)(av[2 * k2 + (s >> 2)][cv][s & 3]);
        #pragma unroll
        for (int tt = 0; tt < 4; tt++)
            #pragma unroll
            for (int s = 0; s < 8; s++) {
                qf[tt][s] = (bf16)(aqk[s >> 2][tt][s & 3] * 0.18257418583505537f);
                kf[tt][s] = (bf16)(aqk[2 + (s >> 2)][tt][s & 3]);
            }
    }
    __builtin_amdgcn_sched_barrier(0);

    // ---- phase 3+4 fused: QK^T + softmax + PV per it (r18). pf[it]'s PV
    // MFMAs issue right after packing, overlapping the next it's QKT/exp.
    f32x4 zacc[4][2];                              // [it][cv]: z[16it+4g+r][16cv+l15]
    #pragma unroll
    for (int it = 0; it < 4; it++) { zacc[it][0] = (f32x4)0.f; zacc[it][1] = (f32x4)0.f; }
    {
        const float* relh = relb + w * 4096;
        #pragma unroll
        for (int it = 0; it < 4; it++) {
            // issue bias loads first: they complete under the QKT MFMAs
            const int i = 16 * it + l15;
            const float* rbb = relh + i * 64 + 4 * g;
            const float* mkb = maskw + i * 64 + 4 * g;
            float4 rb[4], mk[4];
            #pragma unroll
            for (int jt = 0; jt < 4; jt++) {
                rb[jt] = *reinterpret_cast<const float4*>(rbb + 16 * jt);
                mk[jt] = *reinterpret_cast<const float4*>(mkb + 16 * jt);
            }

            f32x4 stj[4];                          // j = 16jt+4g+r
            __builtin_amdgcn_s_setprio(1);
            #pragma unroll
            for (int jt = 0; jt < 4; jt++) stj[jt] = MFMA(kf[jt], qf[it], (f32x4)0.f);
            __builtin_amdgcn_s_setprio(0);

            float sum = 0.f;                       // no-max softmax (r12/r13)
            #pragma unroll
            for (int jt = 0; jt < 4; jt++) {
                const float e0 = __expf(stj[jt][0] + rb[jt].x + mk[jt].x);
                const float e1 = __expf(stj[jt][1] + rb[jt].y + mk[jt].y);
                const float e2 = __expf(stj[jt][2] + rb[jt].z + mk[jt].z);
                const float e3 = __expf(stj[jt][3] + rb[jt].w + mk[jt].w);
                stj[jt][0] = e0; stj[jt][1] = e1; stj[jt][2] = e2; stj[jt][3] = e3;
                sum += (e0 + e1) + (e2 + e3);
            }
            sum += __shfl_xor(sum, 16);
            sum += __shfl_xor(sum, 32);
            const float inv = 1.0f / sum;

            bf16x8 pfc[2];                         // this it's P fragments only
            #pragma unroll
            for (int k2 = 0; k2 < 2; k2++)
                #pragma unroll
                for (int s = 0; s < 8; s++)
                    pfc[k2][s] = (bf16)(stj[2 * k2 + (s >> 2)][s & 3] * inv);

            // PV for this it: 4 MFMAs, overlap next it's VALU work
            __builtin_amdgcn_s_setprio(1);
            #pragma unroll
            for (int k2 = 0; k2 < 2; k2++)
                #pragma unroll
                for (int cv = 0; cv < 2; cv++)
                    zacc[it][cv] = MFMA(pfc[k2], vf[cv][k2], zacc[it][cv]);
            __builtin_amdgcn_s_setprio(0);
        }
    }

    __syncthreads();                               // all waves done reading xb
    // z -> zb (aliases xb; pad cols [180..200) still zero from phase 1)
    #pragma unroll
    for (int cv = 0; cv < 2; cv++) {
        const int d = 16 * cv + l15;
        if (d < 30) {
            #pragma unroll
            for (int it = 0; it < 4; it++)
                #pragma unroll
                for (int r = 0; r < 4; r++)
                    xb[(16 * it + 4 * g + r) * 200 + w * 30 + d] =
                        __builtin_bit_cast(short, (bf16)zacc[it][cv][r]);
        }
    }
    __syncthreads();

    // ---- phase 5: proj GEMM + bias -> out
    f32x4 pa[4][2];
    #pragma unroll
    for (int mt = 0; mt < 4; mt++) { pa[mt][0] = (f32x4)0.f; pa[mt][1] = (f32x4)0.f; }
    #pragma unroll
    for (int ks = 0; ks < 6; ks++) {
        bf16x8 zf[4];
        #pragma unroll
        for (int mt = 0; mt < 4; mt++)
            zf[mt] = *reinterpret_cast<const bf16x8*>(xb + (16 * mt + l15) * 200 + 32 * ks + 8 * g);
        __builtin_amdgcn_s_setprio(1);
        #pragma unroll
        for (int q2 = 0; q2 < 2; q2++) {
            const bf16x8 wf = *reinterpret_cast<const bf16x8*>(
                wprojT + ((2 * w + q2) * 16 + l15) * 192 + 32 * ks + 8 * g);
            #pragma unroll
            for (int mt = 0; mt < 4; mt++)
                pa[mt][q2] = MFMA(zf[mt], wf, pa[mt][q2]);
        }
        __builtin_amdgcn_s_setprio(0);
    }
    #pragma unroll
    for (int q2 = 0; q2 < 2; q2++) {
        const int n = (2 * w + q2) * 16 + l15;
        if (n < 180) {
            const float bn = bproj[n];
            float* const ob = outg + (size_t)b * 11520 + n;
            #pragma unroll
            for (int mt = 0; mt < 4; mt++)
                #pragma unroll
                for (int r = 0; r < 4; r++)
                    ob[(16 * mt + 4 * g + r) * 180] = pa[mt][q2][r] + bn;
        }
    }
}

extern "C" void kernel_launch(void* const* d_in, const int* in_sizes, int n_in,
                              void* d_out, int out_size, void* d_ws, size_t ws_size,
                              hipStream_t stream) {
    const float* windows = (const float*)d_in[0];
    const float* mask    = (const float*)d_in[1];
    const float* wqkv    = (const float*)d_in[2];
    const float* btab    = (const float*)d_in[3];
    const float* wproj   = (const float*)d_in[4];
    const float* bproj   = (const float*)d_in[5];

    bf16*  wqkvT  = (bf16*)d_ws;
    bf16*  wprojT = (bf16*)((char*)d_ws + 221184);
    float* relb   = (float*)((char*)d_ws + 294912);

    hipLaunchKernelGGL(prep_w, dim3(672), dim3(256), 0, stream,
                       wqkv, wproj, btab, wqkvT, wprojT, relb);
    hipLaunchKernelGGL(swin_mfma, dim3(4096), dim3(384), 0, stream,
                       windows, mask, bproj, wqkvT, wprojT, relb, (float*)d_out);
}

// Round 20
// 282.346 us; speedup vs baseline: 1.3926x; 1.3926x over previous
//
#include <hip/hip_runtime.h>

// Swin window attention, fused register-resident MFMA pipeline. 1 block
// (6 waves) per window; wave w owns head w. B=4096, N=64, C=180, H=6, D=30.
//
// Round-20 = round-18 VERBATIM (282.3 us champion). r19's merged-qkv spilled
// (FETCH 261/WRITE 600 MB) -- the 96-reg accumulator block exceeds the
// allocator ceiling; r18's 64-reg aqk is the largest that fits.
//
// Final structure & why (evidence trail):
//   - 6 waves/block, (384,4): any cap <128 spills (r6/r14); 12 waves/CU max.
//   - phases: x->LDS bf16 (batched float4) | merged qk GEMM (swapped mfma)
//     | v GEMM | fused QKT+no-max-softmax+PV per it | z->LDS | proj GEMM.
//   - no-max softmax valid: scores bounded |s|<~7 (validated r12/r13).
//   - fragment-permutation chaining (r2): MFMA contracts A-slot(g,s) with
//     B-slot(g,s); q/k carry d(g,s)=16*(s>=4)+4g+(s&3), P/V carry
//     j(g,s,k2)=32k2+16*(s>=4)+4g+(s&3) -- identical bijections on both
//     operands, so zero cross-lane traffic.
//   - latency plateau, NOT roofline: MfmaUtil 12%, HBM 13%; wall =
//     per-window chain (~35us) x 8 block-rounds/CU at 12 waves/CU.
//
// d_ws (prep_w fills every launch):
//   [0)       wqkvT  bf16 [576][192]  oc = h*96 + sec*32 + d  (0=q,1=k,2=v)
//   [221184)  wprojT bf16 [192][192]  n-major
//   [294912)  relb   f32  [6][64][64] pre-gathered rel-pos bias

typedef __bf16 bf16;
typedef bf16 bf16x8 __attribute__((ext_vector_type(8)));
typedef float f32x4 __attribute__((ext_vector_type(4)));

#define MFMA(a, b, c) __builtin_amdgcn_mfma_f32_16x16x32_bf16(a, b, c, 0, 0, 0)

__global__ void prep_w(const float* __restrict__ wqkv,
                       const float* __restrict__ wproj,
                       const float* __restrict__ btab,
                       bf16* __restrict__ wqkvT,
                       bf16* __restrict__ wprojT,
                       float* __restrict__ relb)
{
    const int idx = blockIdx.x * 256 + threadIdx.x;
    if (idx < 110592) {                          // wqkvT [576][192]
        const int oc = idx / 192, kk = idx - oc * 192;
        const int h = oc / 96, r = oc - h * 96;
        const int sec = r >> 5, d = r & 31;
        wqkvT[idx] = (bf16)((kk < 180 && d < 30) ? wqkv[kk * 540 + sec * 180 + h * 30 + d] : 0.f);
    } else if (idx < 147456) {                   // wprojT [192][192]
        const int r = idx - 110592;
        const int n = r / 192, k = r - n * 192;
        wprojT[r] = (bf16)((n < 180 && k < 180) ? wproj[k * 180 + n] : 0.f);
    } else if (idx < 172032) {                   // relb [6][64][64]
        const int r = idx - 147456;
        const int h = r >> 12;
        const int ij = r & 4095;
        const int i = ij >> 6, j = ij & 63;
        const int rel = ((i >> 3) - (j >> 3) + 7) * 15 + ((i & 7) - (j & 7) + 7);
        relb[r] = btab[rel * 6 + h];
    }
}

__device__ __forceinline__ unsigned pack2(float a, float b) {
    return (unsigned)__builtin_bit_cast(unsigned short, (bf16)a)
         | ((unsigned)__builtin_bit_cast(unsigned short, (bf16)b) << 16);
}

__global__ __launch_bounds__(384, 4)
void swin_mfma(const float* __restrict__ xg_all,
               const float* __restrict__ mask_all,
               const float* __restrict__ bproj,
               const bf16* __restrict__ wqkvT,
               const bf16* __restrict__ wprojT,
               const float* __restrict__ relb,
               float* __restrict__ outg)
{
    __shared__ __align__(16) short xb[64 * 200];   // x bf16, later z bf16

    const int b    = blockIdx.x;
    const int tid  = threadIdx.x;
    const int w    = tid >> 6;                     // wave = head, 0..5
    const int lane = tid & 63;
    const int l15  = lane & 15;
    const int g    = lane >> 4;                    // 0..3

    const float* xg    = xg_all + (size_t)b * 11520;
    const float* maskw = mask_all + (size_t)(b & 1023) * 4096;

    // ---- phase 1: x -> bf16 xb. Batch loads (7-8 float4/thread), then cvt.
    {
        float4 xv[7];
        #pragma unroll
        for (int u = 0; u < 7; u++)
            xv[u] = *reinterpret_cast<const float4*>(xg + 4 * (tid + 384 * u));
        float4 xt;
        if (tid < 192) xt = *reinterpret_cast<const float4*>(xg + 4 * (2688 + tid));
        for (int e = tid; e < 640; e += 384) {     // zero pad cols [180..200)
            const int i = e / 10;
            ((unsigned*)(xb + i * 200 + 180))[e - i * 10] = 0u;
        }
        #pragma unroll
        for (int u = 0; u < 7; u++) {
            const int e = tid + 384 * u;           // float4 index
            const int i = e / 45;
            const int c = 4 * e - i * 180;
            *reinterpret_cast<unsigned*>(xb + i * 200 + c)     = pack2(xv[u].x, xv[u].y);
            *reinterpret_cast<unsigned*>(xb + i * 200 + c + 2) = pack2(xv[u].z, xv[u].w);
        }
        if (tid < 192) {
            const int e = 2688 + tid;
            const int i = e / 45;
            const int c = 4 * e - i * 180;
            *reinterpret_cast<unsigned*>(xb + i * 200 + c)     = pack2(xt.x, xt.y);
            *reinterpret_cast<unsigned*>(xb + i * 200 + c + 2) = pack2(xt.z, xt.w);
        }
    }
    __syncthreads();

    const bf16* wqh = wqkvT + (size_t)(w * 96) * 192;
    const int rowoff = l15 * 192 + 8 * g;

    // ---- phase 2qk: q,k for head w (swapped mfma: lane=token, regs=channels)
    bf16x8 qf[4], kf[4];                           // slot s <-> d = 16*(s>=4)+4g+(s&3)
    {
        f32x4 aqk[4][4];                           // [ct][tt] ct: q0,q1,k0,k1
        #pragma unroll
        for (int ct = 0; ct < 4; ct++)
            #pragma unroll
            for (int tt = 0; tt < 4; tt++) aqk[ct][tt] = (f32x4)0.f;
        #pragma unroll
        for (int ks = 0; ks < 6; ks++) {
            bf16x8 xf[4];
            #pragma unroll
            for (int tt = 0; tt < 4; tt++)
                xf[tt] = *reinterpret_cast<const bf16x8*>(xb + (16 * tt + l15) * 200 + 32 * ks + 8 * g);
            __builtin_amdgcn_s_setprio(1);
            #pragma unroll
            for (int ct = 0; ct < 4; ct++) {
                const bf16x8 wf = *reinterpret_cast<const bf16x8*>(wqh + ct * 3072 + rowoff + 32 * ks);
                #pragma unroll
                for (int tt = 0; tt < 4; tt++)
                    aqk[ct][tt] = MFMA(wf, xf[tt], aqk[ct][tt]);
            }
            __builtin_amdgcn_s_setprio(0);
        }
        #pragma unroll
        for (int tt = 0; tt < 4; tt++)
            #pragma unroll
            for (int s = 0; s < 8; s++) {
                qf[tt][s] = (bf16)(aqk[s >> 2][tt][s & 3] * 0.18257418583505537f);
                kf[tt][s] = (bf16)(aqk[2 + (s >> 2)][tt][s & 3]);
            }
    }
    __builtin_amdgcn_sched_barrier(0);

    // ---- phase 2v: v (normal mfma: lane=channel, regs=tokens)
    bf16x8 vf[2][2];                               // [cv][k2]
    {
        f32x4 av[4][2];                            // [tt][cv]
        #pragma unroll
        for (int tt = 0; tt < 4; tt++) { av[tt][0] = (f32x4)0.f; av[tt][1] = (f32x4)0.f; }
        #pragma unroll
        for (int ks = 0; ks < 6; ks++) {
            bf16x8 xf[4];
            #pragma unroll
            for (int tt = 0; tt < 4; tt++)
                xf[tt] = *reinterpret_cast<const bf16x8*>(xb + (16 * tt + l15) * 200 + 32 * ks + 8 * g);
            __builtin_amdgcn_s_setprio(1);
            #pragma unroll
            for (int cv = 0; cv < 2; cv++) {
                const bf16x8 wf = *reinterpret_cast<const bf16x8*>(wqh + (4 + cv) * 3072 + rowoff + 32 * ks);
                #pragma unroll
                for (int tt = 0; tt < 4; tt++)
                    av[tt][cv] = MFMA(xf[tt], wf, av[tt][cv]);
            }
            __builtin_amdgcn_s_setprio(0);
        }
        #pragma unroll
        for (int cv = 0; cv < 2; cv++)
            #pragma unroll
            for (int k2 = 0; k2 < 2; k2++)
                #pragma unroll
                for (int s = 0; s < 8; s++)
                    vf[cv][k2][s] = (bf16)(av[2 * k2 + (s >> 2)][cv][s & 3]);
    }
    __builtin_amdgcn_sched_barrier(0);

    // ---- phase 3+4 fused: QK^T + softmax + PV per it. pf[it]'s PV MFMAs
    // issue immediately after packing and overlap the next it's QKT/exp.
    f32x4 zacc[4][2];                              // [it][cv]: z[16it+4g+r][16cv+l15]
    #pragma unroll
    for (int it = 0; it < 4; it++) { zacc[it][0] = (f32x4)0.f; zacc[it][1] = (f32x4)0.f; }
    {
        const float* relh = relb + w * 4096;
        #pragma unroll
        for (int it = 0; it < 4; it++) {
            // issue bias loads first: they complete under the QKT MFMAs
            const int i = 16 * it + l15;
            const float* rbb = relh + i * 64 + 4 * g;
            const float* mkb = maskw + i * 64 + 4 * g;
            float4 rb[4], mk[4];
            #pragma unroll
            for (int jt = 0; jt < 4; jt++) {
                rb[jt] = *reinterpret_cast<const float4*>(rbb + 16 * jt);
                mk[jt] = *reinterpret_cast<const float4*>(mkb + 16 * jt);
            }

            f32x4 stj[4];                          // j = 16jt+4g+r
            __builtin_amdgcn_s_setprio(1);
            #pragma unroll
            for (int jt = 0; jt < 4; jt++) stj[jt] = MFMA(kf[jt], qf[it], (f32x4)0.f);
            __builtin_amdgcn_s_setprio(0);

            float sum = 0.f;                       // no-max softmax (r12/r13)
            #pragma unroll
            for (int jt = 0; jt < 4; jt++) {
                const float e0 = __expf(stj[jt][0] + rb[jt].x + mk[jt].x);
                const float e1 = __expf(stj[jt][1] + rb[jt].y + mk[jt].y);
                const float e2 = __expf(stj[jt][2] + rb[jt].z + mk[jt].z);
                const float e3 = __expf(stj[jt][3] + rb[jt].w + mk[jt].w);
                stj[jt][0] = e0; stj[jt][1] = e1; stj[jt][2] = e2; stj[jt][3] = e3;
                sum += (e0 + e1) + (e2 + e3);
            }
            sum += __shfl_xor(sum, 16);
            sum += __shfl_xor(sum, 32);
            const float inv = 1.0f / sum;

            bf16x8 pfc[2];                         // this it's P fragments only
            #pragma unroll
            for (int k2 = 0; k2 < 2; k2++)
                #pragma unroll
                for (int s = 0; s < 8; s++)
                    pfc[k2][s] = (bf16)(stj[2 * k2 + (s >> 2)][s & 3] * inv);

            // PV for this it: 4 MFMAs, overlap next it's VALU work
            __builtin_amdgcn_s_setprio(1);
            #pragma unroll
            for (int k2 = 0; k2 < 2; k2++)
                #pragma unroll
                for (int cv = 0; cv < 2; cv++)
                    zacc[it][cv] = MFMA(pfc[k2], vf[cv][k2], zacc[it][cv]);
            __builtin_amdgcn_s_setprio(0);
        }
    }

    __syncthreads();                               // all waves done reading xb
    // z -> zb (aliases xb; pad cols [180..200) still zero from phase 1)
    #pragma unroll
    for (int cv = 0; cv < 2; cv++) {
        const int d = 16 * cv + l15;
        if (d < 30) {
            #pragma unroll
            for (int it = 0; it < 4; it++)
                #pragma unroll
                for (int r = 0; r < 4; r++)
                    xb[(16 * it + 4 * g + r) * 200 + w * 30 + d] =
                        __builtin_bit_cast(short, (bf16)zacc[it][cv][r]);
        }
    }
    __syncthreads();

    // ---- phase 5: proj GEMM + bias -> out
    f32x4 pa[4][2];
    #pragma unroll
    for (int mt = 0; mt < 4; mt++) { pa[mt][0] = (f32x4)0.f; pa[mt][1] = (f32x4)0.f; }
    #pragma unroll
    for (int ks = 0; ks < 6; ks++) {
        bf16x8 zf[4];
        #pragma unroll
        for (int mt = 0; mt < 4; mt++)
            zf[mt] = *reinterpret_cast<const bf16x8*>(xb + (16 * mt + l15) * 200 + 32 * ks + 8 * g);
        __builtin_amdgcn_s_setprio(1);
        #pragma unroll
        for (int q2 = 0; q2 < 2; q2++) {
            const bf16x8 wf = *reinterpret_cast<const bf16x8*>(
                wprojT + ((2 * w + q2) * 16 + l15) * 192 + 32 * ks + 8 * g);
            #pragma unroll
            for (int mt = 0; mt < 4; mt++)
                pa[mt][q2] = MFMA(zf[mt], wf, pa[mt][q2]);
        }
        __builtin_amdgcn_s_setprio(0);
    }
    #pragma unroll
    for (int q2 = 0; q2 < 2; q2++) {
        const int n = (2 * w + q2) * 16 + l15;
        if (n < 180) {
            const float bn = bproj[n];
            float* const ob = outg + (size_t)b * 11520 + n;
            #pragma unroll
            for (int mt = 0; mt < 4; mt++)
                #pragma unroll
                for (int r = 0; r < 4; r++)
                    ob[(16 * mt + 4 * g + r) * 180] = pa[mt][q2][r] + bn;
        }
    }
}

extern "C" void kernel_launch(void* const* d_in, const int* in_sizes, int n_in,
                              void* d_out, int out_size, void* d_ws, size_t ws_size,
                              hipStream_t stream) {
    const float* windows = (const float*)d_in[0];
    const float* mask    = (const float*)d_in[1];
    const float* wqkv    = (const float*)d_in[2];
    const float* btab    = (const float*)d_in[3];
    const float* wproj   = (const float*)d_in[4];
    const float* bproj   = (const float*)d_in[5];

    bf16*  wqkvT  = (bf16*)d_ws;
    bf16*  wprojT = (bf16*)((char*)d_ws + 221184);
    float* relb   = (float*)((char*)d_ws + 294912);

    hipLaunchKernelGGL(prep_w, dim3(672), dim3(256), 0, stream,
                       wqkv, wproj, btab, wqkvT, wprojT, relb);
    hipLaunchKernelGGL(swin_mfma, dim3(4096), dim3(384), 0, stream,
                       windows, mask, bproj, wqkvT, wprojT, relb, (float*)d_out);
}